// Round 25
// baseline (443.499 us; speedup 1.0000x reference)
//
#include <hip/hip_runtime.h>
#include <hip/hip_fp16.h>
#include <math.h>

#define TT 8192
#define FF 64
#define TILE 64
#define HALO 50
#define SROWS 82             // staged halo rows per block (split FIR)
#define XSTR 72              // f16 row stride for xsH (144B, 16B-aligned)

typedef float f32x2 __attribute__((ext_vector_type(2)));
typedef float f32x4 __attribute__((ext_vector_type(4)));
typedef _Float16 f16x8 __attribute__((ext_vector_type(8)));
typedef unsigned int u32x4 __attribute__((ext_vector_type(4)));
typedef unsigned int u32x2 __attribute__((ext_vector_type(2)));

__device__ __forceinline__ float rcpf(float x) { return __builtin_amdgcn_rcpf(x); }

// ---- prep: wsmT[j*64+i] = f32 softmax(W)[i][j]; pwB = f16 MFMA B-frags of PW;
//      cpad2[65]: cpad2[q] = coeffs[q-7] for 0<=q-7<=50 else 0
__global__ void prep_kernel(const float* __restrict__ W, const float* __restrict__ PW,
                            const float* __restrict__ C,
                            float* __restrict__ wsmT, u32x4* __restrict__ pwB,
                            float* __restrict__ cpad2) {
    const int lane = threadIdx.x;
    const int wv   = threadIdx.y;
    const int tid  = wv * 64 + lane;
    for (int it = 0; it < 16; ++it) {
        const int r = wv * 16 + it;
        float v = W[r * 64 + lane];
        float m = v;
        #pragma unroll
        for (int off = 32; off >= 1; off >>= 1)
            m = fmaxf(m, __shfl_xor(m, off, 64));
        float e = __expf(v - m);
        float s = e;
        #pragma unroll
        for (int off = 32; off >= 1; off >>= 1)
            s += __shfl_xor(s, off, 64);
        wsmT[lane * 64 + r] = e * rcpf(s);     // [j][i] f32
    }
    for (int s = tid; s < 512; s += 256) {
        const int n2 = s >> 6;
        const int ln = s & 63;
        const int i  = (n2 >> 1) * 16 + (ln & 15);
        const int k0 = (n2 & 1) * 32 + (ln >> 4) * 8;
        u32x4 frag;
        #pragma unroll
        for (int w = 0; w < 4; ++w) {
            const unsigned lo = __half_as_ushort(__float2half_rn(PW[i * 64 + k0 + 2 * w]));
            const unsigned hi = __half_as_ushort(__float2half_rn(PW[i * 64 + k0 + 2 * w + 1]));
            frag[w] = lo | (hi << 16);
        }
        pwB[s] = frag;
    }
    if (tid < 65) {
        const int k = tid - 7;
        cpad2[tid] = (k >= 0 && k <= 50) ? C[k] : 0.f;
    }
}

// ---- fused main: 512 thr / 8 waves; each block = half the features of a 64-row tile ----
__global__ __launch_bounds__(512, 8)
void mcao_main(const float* __restrict__ x,
               const float* __restrict__ wsm,
               const u32x4* __restrict__ pwB,
               const float* __restrict__ cpad2,
               const float* __restrict__ pb,
               const float* __restrict__ kap,
               float* __restrict__ out,
               float* __restrict__ memout) {
    // LDS 36768 B -> 4 blocks/CU (grid 1024 = exactly 4/CU = 32 waves/CU):
    //   [0, 11808)      xsH f16 [82][72]   FIR stream (this block's 32 rows + halo)
    //   [11808, 28448)  tS  f32 [64][65]   tanh[feat][row]; P2 f32 [32][65] overlays after bar2
    //   [28448, 36768)  uH  f16 [64][65]   e^-|x|[feat][row]
    __shared__ __align__(16) char smem[36768];
    __half* xsH = (__half*)smem;
    float*  tS  = (float*)(smem + 11808);
    float*  P2  = (float*)(smem + 11808);
    __half* uH  = (__half*)(smem + 28448);

    const int tid  = threadIdx.x;
    const int lane = tid & 63;
    const int wv   = tid >> 6;              // 0..7

    const int bid   = (int)blockIdx.x;
    const int fblk  = bid >> 9;             // 0/1: feature half
    const int tid0  = bid & 511;            // tile id
    // XCD-aware bijective swizzle on tiles: 512 tiles -> 64 consecutive per XCD
    const int sw = (tid0 & 7) * 64 + (tid0 >> 3);
    const int b  = sw >> 7;                 // 0..3
    const int t0 = (sw & 127) * TILE;
    const float* xb = x + (size_t)b * TT * FF;

    const int tbase = t0 - HALO + 32 * fblk;   // xsH row 0 <-> global row tbase

    // ---- stage xsH (f16): 82 rows starting at tbase ----
    for (int i4 = tid; i4 < SROWS * 16; i4 += 512) {
        const int s = i4 >> 4, f4 = i4 & 15, t = tbase + s;
        f32x4 v = {0.f, 0.f, 0.f, 0.f};
        if (t >= 0) v = *(const f32x4*)(xb + (size_t)t * 64 + f4 * 4);
        __half hv[4];
        #pragma unroll
        for (int q = 0; q < 4; ++q) hv[q] = __float2half_rn(v[q]);
        *(u32x2*)(&xsH[s * XSTR + f4 * 4]) = *(u32x2*)hv;
    }
    // ---- planes: all 64 rows x 64 feats; thread -> (row = tid>>3, feats (tid&7)*8..+7) ----
    {
        const int row = tid >> 3, f0 = (tid & 7) * 8;
        #pragma unroll
        for (int c4 = 0; c4 < 2; ++c4) {
            const f32x4 v = *(const f32x4*)(xb + (size_t)(t0 + row) * 64 + f0 + c4 * 4);
            #pragma unroll
            for (int q = 0; q < 4; ++q) {
                const int f = f0 + c4 * 4 + q;
                tS[f * 65 + row] = fmaf(-2.f, rcpf(__expf(2.f * v[q]) + 1.f), 1.f);
                uH[f * 65 + row] = __float2half(__expf(-fabsf(v[q])));
            }
        }
    }
    __syncthreads();                                    // bar1

    // ---- proj via MFMA: wave -> C-tile (mt = wv>>1 rows, nt = fblk*2 + (wv&1) cols);
    //      A-frags from global (L2-hot) ----
    const int mt = wv >> 1, ntl = wv & 1;
    const int nt = fblk * 2 + ntl;
    const int mrow = mt * 16 + (lane & 15);
    const int kcol = (lane >> 4) * 8;
    f32x4 cfr = {0.f, 0.f, 0.f, 0.f};
    #pragma unroll
    for (int kt = 0; kt < 2; ++kt) {
        const f32x4 alo = *(const f32x4*)(xb + (size_t)(t0 + mrow) * 64 + kt * 32 + kcol);
        const f32x4 ahi = *(const f32x4*)(xb + (size_t)(t0 + mrow) * 64 + kt * 32 + kcol + 4);
        f16x8 afr;
        #pragma unroll
        for (int q = 0; q < 4; ++q) {
            afr[q]     = (_Float16)alo[q];
            afr[q + 4] = (_Float16)ahi[q];
        }
        const f16x8 bfr = __builtin_bit_cast(f16x8, pwB[(nt * 2 + kt) * 64 + lane]);
        cfr = __builtin_amdgcn_mfma_f32_16x16x32_f16(afr, bfr, cfr, 0, 0, 0);
    }

    // ---- megaloop setup: lane = row r; wave's 4 GLOBAL feats gib..gib+3 (uniform) ----
    const int r    = lane;
    const int lf_u = __builtin_amdgcn_readfirstlane(wv * 4);       // local feat base 0..28
    const int gib  = __builtin_amdgcn_readfirstlane(fblk * 32 + wv * 4);  // global feat base
    const float* wbase = wsm + gib;
    f32x2 tiP[2], uiP[2];
    #pragma unroll
    for (int q = 0; q < 4; ++q) {
        tiP[q >> 1][q & 1] = tS[(gib + q) * 65 + r];
        uiP[q >> 1][q & 1] = __half2float(uH[(gib + q) * 65 + r]);
    }

    float macc[4] = {0.f, 0.f, 0.f, 0.f};
    f32x2 cac[2] = {{0.f, 0.f}, {0.f, 0.f}};
    const f32x2 one2 = {1.f, 1.f};
    const int firrow = 4 * wv;              // local FIR out-row base (0..28)

    // ---- megaloop m = 0..63: coupling all m (w via s_load); FIR for m < 54 ----
    #pragma unroll
    for (int m = 0; m < 64; ++m) {
        const float tj = tS[m * 65 + r];                 // b32, consecutive: free
        const float uj = __half2float(uH[m * 65 + r]);   // u16, consecutive: free
        const f32x4 wA = *(const f32x4*)(wbase + m * 64);  // uniform -> s_load_dwordx4
        if (m < 54) {
            const float xv = __half2float(xsH[(firrow + m) * XSTR + lane]);
            #pragma unroll
            for (int r2 = 0; r2 < 4; ++r2)
                macc[r2] = fmaf(cpad2[r2 + 57 - m], xv, macc[r2]);  // SGPR coeff
        }
        const f32x2 tjj = {tj, tj}, ujj = {uj, uj};
        #pragma unroll
        for (int g = 0; g < 2; ++g) {
            const f32x2 d1  = __builtin_elementwise_fma(-tiP[g], tjj, one2);
            const f32x2 d2  = __builtin_elementwise_fma( uiP[g], ujj, one2);
            const f32x2 den = d1 * d2;
            f32x2 rr; rr.x = rcpf(den.x); rr.y = rcpf(den.y);
            const f32x2 s = (tiP[g] - tjj) * rr;
            f32x2 wg; wg.x = wA[2 * g]; wg.y = wA[2 * g + 1];
            cac[g] = __builtin_elementwise_fma(wg, s, cac[g]);   // pk_fma, SGPR-pair w
        }
    }

    // ---- memory-term store: this block's rows 32*fblk + firrow + r2 ----
    #pragma unroll
    for (int r2 = 0; r2 < 4; ++r2)
        memout[(size_t)(b * TT + t0 + 32 * fblk + firrow + r2) * 64 + lane] = macc[r2];

    __syncthreads();                                    // bar2 (tS/uH reads done)

    // ---- proj C-frag -> P2 (local cols 0..31, overlays tS) ----
    {
        const int ic = ntl * 16 + (lane & 15);          // local col
        const int rb = mt * 16 + (lane >> 4) * 4;
        #pragma unroll
        for (int reg = 0; reg < 4; ++reg)
            P2[ic * 65 + rb + reg] = cfr[reg];
    }
    __syncthreads();                                    // bar3

    // ---- epilogue RMW: P2 <- 0.4c + 0.3(proj+pb)ksum  (local feats lf_u..+3) ----
    const float kappa = kap[0];
    const float ksum  = (1.f - __expf(-kappa * (float)(t0 + r + 1))) *
                        rcpf(1.f - __expf(-kappa));
    #pragma unroll
    for (int q = 0; q < 4; ++q) {
        const float cv  = (q & 1) ? cac[q >> 1].y : cac[q >> 1].x;
        const int   idx = (lf_u + q) * 65 + r;
        P2[idx] = fmaf(0.4f, cv, 0.3f * (P2[idx] + pb[gib + q]) * ksum);
    }
    __syncthreads();                                    // bar4

    // ---- final store: 64 rows x 32 local feats; wave wv -> rows 8wv..8wv+7 ----
    #pragma unroll
    for (int p = 0; p < 4; ++p) {
        const int row = 8 * wv + 2 * p + (lane >> 5);
        const int lf  = lane & 31;
        out[(size_t)(b * TT + t0 + row) * 64 + fblk * 32 + lf] =
            P2[lf * 65 + row];
    }
}

// memout is written by mcao_main; out needs 0.3*m added for rows/feature-halves:
// NOTE: out = 0.4c + 0.3(proj+pb)ksum stored above lacks 0.3*m; add via P2? ->
// handled here: separate pass fused into store would need macc for ALL rows.
// Instead: small add kernel reading memout (L2-hot) and adding into out.
__global__ __launch_bounds__(256, 8)
void addmem_kernel(const float* __restrict__ memout, float* __restrict__ out) {
    const size_t i = (size_t)blockIdx.x * 256 + threadIdx.x;
    const f32x4 m4 = ((const f32x4*)memout)[i];
    f32x4 o4 = ((f32x4*)out)[i];
    o4.x = fmaf(0.3f, m4.x, o4.x);
    o4.y = fmaf(0.3f, m4.y, o4.y);
    o4.z = fmaf(0.3f, m4.z, o4.z);
    o4.w = fmaf(0.3f, m4.w, o4.w);
    ((f32x4*)out)[i] = o4;
}

extern "C" void kernel_launch(void* const* d_in, const int* in_sizes, int n_in,
                              void* d_out, int out_size, void* d_ws, size_t ws_size,
                              hipStream_t stream) {
    const float* x   = (const float*)d_in[0];
    const float* W   = (const float*)d_in[1];
    const float* PW  = (const float*)d_in[2];
    const float* pb  = (const float*)d_in[3];
    const float* kap = (const float*)d_in[4];
    const float* cf  = (const float*)d_in[5];

    float* out    = (float*)d_out;
    float* memout = out + (size_t)4 * TT * FF;

    float*  wsmT  = (float*)d_ws;                        // 16 KB
    u32x4*  pwB   = (u32x4*)((char*)d_ws + 16384);       //  8 KB
    float*  cpad2 = (float*)((char*)d_ws + 24576);       // 260 B

    hipLaunchKernelGGL(prep_kernel, dim3(1), dim3(64, 4), 0, stream,
                       W, PW, cf, wsmT, pwB, cpad2);
    hipLaunchKernelGGL(mcao_main, dim3(2 * 4 * (TT / TILE)), dim3(512), 0, stream,
                       x, wsmT, pwB, cpad2, pb, kap, out, memout);
    hipLaunchKernelGGL(addmem_kernel, dim3(4 * TT * FF / 4 / 256), dim3(256), 0, stream,
                       memout, out);
}

// Round 26
// 99.113 us; speedup vs baseline: 4.4747x; 4.4747x over previous
//
#include <hip/hip_runtime.h>
#include <hip/hip_fp16.h>
#include <math.h>

#define TT 8192
#define FF 64
#define TILE 64
#define HALO 50
#define ROWS 114             // TILE + HALO
#define XSTR 68              // f16 row stride for xsH (136B, 8B-aligned rows)

typedef float f32x2 __attribute__((ext_vector_type(2)));
typedef float f32x4 __attribute__((ext_vector_type(4)));
typedef _Float16 f16x8 __attribute__((ext_vector_type(8)));
typedef unsigned int u32x4 __attribute__((ext_vector_type(4)));
typedef unsigned int u32x2 __attribute__((ext_vector_type(2)));

__device__ __forceinline__ float rcpf(float x) { return __builtin_amdgcn_rcpf(x); }

// ---- prep: wsmT[j*64+i] = f32 softmax(W)[i][j]; pwB = f16 MFMA B-frags of PW;
//      cpad2[65]: cpad2[q] = coeffs[q-7] for 0<=q-7<=50 else 0
__global__ void prep_kernel(const float* __restrict__ W, const float* __restrict__ PW,
                            const float* __restrict__ C,
                            float* __restrict__ wsmT, u32x4* __restrict__ pwB,
                            float* __restrict__ cpad2) {
    const int lane = threadIdx.x;
    const int wv   = threadIdx.y;
    const int tid  = wv * 64 + lane;
    for (int it = 0; it < 16; ++it) {
        const int r = wv * 16 + it;
        float v = W[r * 64 + lane];
        float m = v;
        #pragma unroll
        for (int off = 32; off >= 1; off >>= 1)
            m = fmaxf(m, __shfl_xor(m, off, 64));
        float e = __expf(v - m);
        float s = e;
        #pragma unroll
        for (int off = 32; off >= 1; off >>= 1)
            s += __shfl_xor(s, off, 64);
        wsmT[lane * 64 + r] = e * rcpf(s);     // [j][i] f32
    }
    for (int s = tid; s < 512; s += 256) {
        const int n2 = s >> 6;
        const int ln = s & 63;
        const int i  = (n2 >> 1) * 16 + (ln & 15);
        const int k0 = (n2 & 1) * 32 + (ln >> 4) * 8;
        u32x4 frag;
        #pragma unroll
        for (int w = 0; w < 4; ++w) {
            const unsigned lo = __half_as_ushort(__float2half_rn(PW[i * 64 + k0 + 2 * w]));
            const unsigned hi = __half_as_ushort(__float2half_rn(PW[i * 64 + k0 + 2 * w + 1]));
            frag[w] = lo | (hi << 16);
        }
        pwB[s] = frag;
    }
    if (tid < 65) {
        const int k = tid - 7;
        cpad2[tid] = (k >= 0 && k <= 50) ? C[k] : 0.f;
    }
}

// ---- fused main: 512 thr / 8 waves; block = (tile, feature-half); lane = row ----
__global__ __launch_bounds__(512, 4)
void mcao_main(const float* __restrict__ x,
               const float* __restrict__ wsm,
               const u32x4* __restrict__ pwB,
               const float* __restrict__ cpad2,
               const float* __restrict__ pb,
               const float* __restrict__ kap,
               float* __restrict__ out,
               float* __restrict__ memout) {
    // LDS 40336 B -> rounds to 40448 -> 4 blocks/CU (grid 1024 = exactly 4/CU):
    //   [0, 15504)      xsH f16 [114][68]  FIR stream + MFMA-A
    //   [15504, 32144)  tS  f32 [64][65]   tanh[feat][row]; P2 f32 [32][65] overlays after bar2
    //   [32144, 40336)  uH  f16 [64][64]   e^-|x|[feat][row]
    __shared__ __align__(16) char smem[40336];
    __half* xsH = (__half*)smem;
    float*  tS  = (float*)(smem + 15504);
    float*  P2  = (float*)(smem + 15504);
    __half* uH  = (__half*)(smem + 32144);

    const int tid  = threadIdx.x;
    const int lane = tid & 63;
    const int wv   = tid >> 6;              // 0..7

    const int bid  = (int)blockIdx.x;
    const int fblk = bid >> 9;              // 0/1: feature half (pair shares XCD: 512%8==0)
    const int tid0 = bid & 511;             // tile id
    const int sw = (tid0 & 7) * 64 + (tid0 >> 3);   // XCD swizzle on tiles
    const int b  = sw >> 7;                 // 0..3
    const int t0 = (sw & 127) * TILE;
    const float* xb = x + (size_t)b * TT * FF;

    // ---- stage xsH (f16): 114 rows from t0-50 ----
    for (int i4 = tid; i4 < ROWS * 16; i4 += 512) {
        const int s = i4 >> 4, f4 = i4 & 15, t = t0 - HALO + s;
        f32x4 v = {0.f, 0.f, 0.f, 0.f};
        if (t >= 0) v = *(const f32x4*)(xb + (size_t)t * 64 + f4 * 4);
        __half hv[4];
        #pragma unroll
        for (int q = 0; q < 4; ++q) hv[q] = __float2half_rn(v[q]);
        *(u32x2*)(&xsH[s * XSTR + f4 * 4]) = *(u32x2*)hv;
    }
    // ---- planes: thread -> (row = tid>>3, feats (tid&7)*8..+7), f32 source ----
    {
        const int row = tid >> 3, f0 = (tid & 7) * 8;
        #pragma unroll
        for (int c4 = 0; c4 < 2; ++c4) {
            const f32x4 v = *(const f32x4*)(xb + (size_t)(t0 + row) * 64 + f0 + c4 * 4);
            #pragma unroll
            for (int q = 0; q < 4; ++q) {
                const int f = f0 + c4 * 4 + q;
                tS[f * 65 + row] = fmaf(-2.f, rcpf(__expf(2.f * v[q]) + 1.f), 1.f);
                uH[f * 64 + row] = __float2half(__expf(-fabsf(v[q])));
            }
        }
    }
    __syncthreads();                                    // bar1

    // ---- proj via MFMA: wave -> C-tile (mt = wv>>1, local col-tile ntl = wv&1) ----
    const int mt = wv >> 1, ntl = wv & 1;
    const int nt = fblk * 2 + ntl;                      // global col-tile
    const int marow = HALO + mt * 16 + (lane & 15);
    const int kcol  = (lane >> 4) * 8;
    f32x4 cfr = {0.f, 0.f, 0.f, 0.f};
    #pragma unroll
    for (int kt = 0; kt < 2; ++kt) {
        f16x8 afr;
        *(u32x2*)&afr       = *(const u32x2*)(&xsH[marow * XSTR + kt * 32 + kcol]);
        *((u32x2*)&afr + 1) = *(const u32x2*)(&xsH[marow * XSTR + kt * 32 + kcol + 4]);
        const f16x8 bfr = __builtin_bit_cast(f16x8, pwB[(nt * 2 + kt) * 64 + lane]);
        cfr = __builtin_amdgcn_mfma_f32_16x16x32_f16(afr, bfr, cfr, 0, 0, 0);
    }

    // ---- megaloop setup: lane = row r; wave's 4 GLOBAL feats gib..+3 (uniform) ----
    const int r    = lane;
    const int lf_u = __builtin_amdgcn_readfirstlane(wv * 4);            // local feat base
    const int gib  = __builtin_amdgcn_readfirstlane(fblk * 32 + wv * 4);
    const float* wbase = wsm + gib;
    f32x2 tiP[2], uiP[2];
    #pragma unroll
    for (int q = 0; q < 4; ++q) {
        tiP[q >> 1][q & 1] = tS[(gib + q) * 65 + r];
        uiP[q >> 1][q & 1] = __half2float(uH[(gib + q) * 64 + r]);
    }

    float macc[8] = {0,0,0,0,0,0,0,0};
    f32x2 cac[2] = {{0.f, 0.f}, {0.f, 0.f}};
    const f32x2 one2 = {1.f, 1.f};
    const int firrow = 8 * wv;              // FIR rows 8wv..8wv+7 (all 64 rows covered)

    // ---- megaloop m = 0..63: coupling all m (w via s_load); FIR for m < 58 ----
    #pragma unroll
    for (int m = 0; m < 64; ++m) {
        const float tj = tS[m * 65 + r];                 // b32, conflict-free
        const float uj = __half2float(uH[m * 64 + r]);   // u16, conflict-free
        const f32x4 wA = *(const f32x4*)(wbase + m * 64);  // uniform -> s_load_dwordx4
        if (m < 58) {
            const float xv = __half2float(xsH[(firrow + m) * XSTR + lane]);
            #pragma unroll
            for (int r2 = 0; r2 < 8; ++r2)
                macc[r2] = fmaf(cpad2[r2 + 57 - m], xv, macc[r2]);  // SGPR coeff
        }
        const f32x2 tjj = {tj, tj}, ujj = {uj, uj};
        #pragma unroll
        for (int g = 0; g < 2; ++g) {
            const f32x2 d1  = __builtin_elementwise_fma(-tiP[g], tjj, one2);
            const f32x2 d2  = __builtin_elementwise_fma( uiP[g], ujj, one2);
            const f32x2 den = d1 * d2;
            f32x2 rr; rr.x = rcpf(den.x); rr.y = rcpf(den.y);
            const f32x2 s = (tiP[g] - tjj) * rr;
            f32x2 wg; wg.x = wA[2 * g]; wg.y = wA[2 * g + 1];
            cac[g] = __builtin_elementwise_fma(wg, s, cac[g]);   // pk_fma, SGPR-pair w
        }
    }

    // ---- memory-term store (fblk 0 only; values identical across the pair) ----
    if (fblk == 0) {
        #pragma unroll
        for (int r2 = 0; r2 < 8; ++r2)
            memout[(size_t)(b * TT + t0 + firrow + r2) * 64 + lane] = macc[r2];
    }

    __syncthreads();                                    // bar2 (tS/uH reads done)

    // ---- proj C-frag -> P2 (local cols 0..31, overlays tS) ----
    {
        const int ic = ntl * 16 + (lane & 15);
        const int rb = mt * 16 + (lane >> 4) * 4;
        #pragma unroll
        for (int reg = 0; reg < 4; ++reg)
            P2[ic * 65 + rb + reg] = cfr[reg];
    }
    __syncthreads();                                    // bar3

    // ---- epilogue RMW: P2 <- 0.4c + 0.3(proj+pb)ksum ----
    const float kappa = kap[0];
    const float ksum  = (1.f - __expf(-kappa * (float)(t0 + r + 1))) *
                        rcpf(1.f - __expf(-kappa));
    #pragma unroll
    for (int q = 0; q < 4; ++q) {
        const float cv  = (q & 1) ? cac[q >> 1].y : cac[q >> 1].x;
        const int   idx = (lf_u + q) * 65 + r;
        P2[idx] = fmaf(0.4f, cv, 0.3f * (P2[idx] + pb[gib + q]) * ksum);
    }
    __syncthreads();                                    // bar4

    // ---- add 0.3*macc into P2 for this block's feats (cell-disjoint) ----
    if ((lane >> 5) == fblk) {
        const int lf = lane & 31;
        #pragma unroll
        for (int r2 = 0; r2 < 8; ++r2) {
            const int idx = lf * 65 + firrow + r2;
            P2[idx] = fmaf(0.3f, macc[r2], P2[idx]);
        }
    }
    __syncthreads();                                    // bar5

    // ---- final store: 64 rows x 32 local feats; wave wv -> rows 8wv..8wv+7 ----
    #pragma unroll
    for (int p = 0; p < 4; ++p) {
        const int row = 8 * wv + 2 * p + (lane >> 5);
        const int lf  = lane & 31;
        out[(size_t)(b * TT + t0 + row) * 64 + fblk * 32 + lf] = P2[lf * 65 + row];
    }
}

extern "C" void kernel_launch(void* const* d_in, const int* in_sizes, int n_in,
                              void* d_out, int out_size, void* d_ws, size_t ws_size,
                              hipStream_t stream) {
    const float* x   = (const float*)d_in[0];
    const float* W   = (const float*)d_in[1];
    const float* PW  = (const float*)d_in[2];
    const float* pb  = (const float*)d_in[3];
    const float* kap = (const float*)d_in[4];
    const float* cf  = (const float*)d_in[5];

    float* out    = (float*)d_out;
    float* memout = out + (size_t)4 * TT * FF;

    float*  wsmT  = (float*)d_ws;                        // 16 KB
    u32x4*  pwB   = (u32x4*)((char*)d_ws + 16384);       //  8 KB
    float*  cpad2 = (float*)((char*)d_ws + 24576);       // 260 B

    hipLaunchKernelGGL(prep_kernel, dim3(1), dim3(64, 4), 0, stream,
                       W, PW, cf, wsmT, pwB, cpad2);
    hipLaunchKernelGGL(mcao_main, dim3(2 * 4 * (TT / TILE)), dim3(512), 0, stream,
                       x, wsmT, pwB, cpad2, pb, kap, out, memout);
}